// Round 1
// baseline (174.946 us; speedup 1.0000x reference)
//
#include <hip/hip_runtime.h>
#include <hip/hip_bf16.h>
#include <cstdint>

#define DEV static __device__ __forceinline__

typedef unsigned short u16t;
typedef __attribute__((ext_vector_type(4))) float f32x4;
typedef __attribute__((ext_vector_type(4))) unsigned short u16x4;
typedef __attribute__((ext_vector_type(8))) unsigned short u16x8;
typedef __attribute__((ext_vector_type(8))) __bf16 bf16x8;

DEV u16t f2bf(float f) {
  unsigned u = __builtin_bit_cast(unsigned, f);
  u += 0x7fffu + ((u >> 16) & 1u);
  return (u16t)(u >> 16);
}
DEV float bf2f(u16t h) {
  unsigned u = ((unsigned)h) << 16;
  return __builtin_bit_cast(float, u);
}

DEV void gload_lds16(const void* g, void* l) {
  __builtin_amdgcn_global_load_lds(
      (const __attribute__((address_space(1))) void*)g,
      (__attribute__((address_space(3))) void*)l, 16, 0, 0);
}

DEV bf16x8 ldsfrag(const u16t* p) {
  return __builtin_bit_cast(bf16x8, *(const u16x8*)p);
}

// ---------------- convert x (fp32 -> bf16) ----------------
__global__ __launch_bounds__(256) void k_convert_x(const float* __restrict__ x,
                                                   u16t* __restrict__ xb) {
  int i = (blockIdx.x * 256 + threadIdx.x) * 4;
  f32x4 v = *(const f32x4*)&x[i];
  u16x4 o;
#pragma unroll
  for (int j = 0; j < 4; ++j) o[j] = f2bf(v[j]);
  *(u16x4*)&xb[i] = o;
}

// ------------- transpose + convert weights (fp32 [K][N] -> bf16 [N][K]) -------------
__global__ __launch_bounds__(256) void k_transw(const float* __restrict__ w0,
                                                const float* __restrict__ w1,
                                                const float* __restrict__ w2,
                                                const float* __restrict__ w3,
                                                u16t* __restrict__ qkvT,
                                                u16t* __restrict__ oT) {
  __shared__ float lds[64][68];
  int z = blockIdx.z;
  const float* W = (z == 0) ? w0 : (z == 1) ? w1 : (z == 2) ? w2 : w3;
  u16t* OUT = (z < 3) ? (qkvT + (size_t)z * 1024 * 1024) : oT;
  int k0 = blockIdx.x * 64, n0 = blockIdx.y * 64;
  int t = threadIdx.x;
  int kl = t >> 4, n4 = (t & 15) << 2;
#pragma unroll
  for (int p = 0; p < 4; ++p) {
    f32x4 v = *(const f32x4*)&W[(size_t)(k0 + kl + p * 16) * 1024 + n0 + n4];
    *(f32x4*)&lds[kl + p * 16][n4] = v;
  }
  __syncthreads();
  int nl = t >> 4, k4 = (t & 15) << 2;
#pragma unroll
  for (int p = 0; p < 4; ++p) {
    int n = nl + p * 16;
    u16x4 o;
#pragma unroll
    for (int i = 0; i < 4; ++i) o[i] = f2bf(lds[k4 + i][n]);
    *(u16x4*)&OUT[(size_t)(n0 + n) * 1024 + k0 + k4] = o;
  }
}

// ---------------- GEMM: C[M,N] = A[M,K] * BT[N,K]^T + bias ----------------
// 128x128 tile, BK=64, 4 waves (2x2), each wave 64x64 (4x4 frags of 16x16).
// LDS XOR-swizzled in 16B slots; global source pre-inverse-swizzled so
// global_load_lds can write linearly.
template <bool BF16_OUT>
__global__ __launch_bounds__(256) void k_gemm_bt(const u16t* __restrict__ A,
                                                 const u16t* __restrict__ BT,
                                                 void* __restrict__ Cout,
                                                 const float* __restrict__ b0,
                                                 const float* __restrict__ b1,
                                                 const float* __restrict__ b2,
                                                 int M, int N, int K) {
  __shared__ u16t Al[128 * 64];
  __shared__ u16t Bl[128 * 64];
  const int tid = threadIdx.x;
  const int l = tid & 63;
  const int w = tid >> 6;
  const int m0 = blockIdx.x * 128, n0 = blockIdx.y * 128;
  const int wm = (w >> 1) * 64, wn = (w & 1) * 64;
  const int lm = l & 15, lh = l >> 4;
  f32x4 acc[4][4] = {};

  const int nt = K >> 6;
  for (int t = 0; t < nt; ++t) {
    const int k0 = t << 6;
#pragma unroll
    for (int s = 0; s < 4; ++s) {
      int c = s * 256 + tid;
      int row = c >> 3, slot = c & 7;
      int ks = k0 + (((slot ^ (row & 7)) & 7) << 3);
      gload_lds16(A + (size_t)(m0 + row) * K + ks, &Al[c * 8]);
    }
#pragma unroll
    for (int s = 0; s < 4; ++s) {
      int c = s * 256 + tid;
      int row = c >> 3, slot = c & 7;
      int ks = k0 + (((slot ^ (row & 7)) & 7) << 3);
      gload_lds16(BT + (size_t)(n0 + row) * K + ks, &Bl[c * 8]);
    }
    asm volatile("s_waitcnt vmcnt(0)" ::: "memory");
    __syncthreads();

#pragma unroll
    for (int kk = 0; kk < 2; ++kk) {
      bf16x8 af[4], bfr[4];
#pragma unroll
      for (int i = 0; i < 4; ++i) {
        int ra = wm + i * 16 + lm;
        int sa = (kk * 4 + lh) ^ (ra & 7);
        af[i] = ldsfrag(&Al[ra * 64 + sa * 8]);
        int rb = wn + i * 16 + lm;
        int sb = (kk * 4 + lh) ^ (rb & 7);
        bfr[i] = ldsfrag(&Bl[rb * 64 + sb * 8]);
      }
#pragma unroll
      for (int i = 0; i < 4; ++i)
#pragma unroll
        for (int j = 0; j < 4; ++j)
          acc[i][j] = __builtin_amdgcn_mfma_f32_16x16x32_bf16(af[i], bfr[j],
                                                              acc[i][j], 0, 0, 0);
    }
    __syncthreads();
  }

#pragma unroll
  for (int i = 0; i < 4; ++i) {
    int row = m0 + wm + i * 16 + (lh << 2);
#pragma unroll
    for (int j = 0; j < 4; ++j) {
      int col = n0 + wn + j * 16 + lm;
      const float* bp = (col < 1024) ? b0 : ((col < 2048) ? b1 : b2);
      float bias = bp[col & 1023];
#pragma unroll
      for (int r = 0; r < 4; ++r) {
        float v = acc[i][j][r] + bias;
        if (BF16_OUT)
          ((u16t*)Cout)[(size_t)(row + r) * N + col] = f2bf(v);
        else
          ((float*)Cout)[(size_t)(row + r) * N + col] = v;
      }
    }
  }
}

// ---------------- transpose V: qkv[:, 2048+h*64+d] -> vt[bh][d][s] ----------------
__global__ __launch_bounds__(256) void k_transv(const u16t* __restrict__ qkv,
                                                u16t* __restrict__ vt) {
  __shared__ u16t lds[64][80];
  int bh = blockIdx.y, b = bh >> 4, h = bh & 15;
  int s0 = blockIdx.x * 64;
  int t = threadIdx.x;
  int sl = t >> 2, d16 = (t & 3) << 4;
  const u16t* src = qkv + (size_t)(b * 2048 + s0 + sl) * 3072 + 2048 + h * 64 + d16;
  *(u16x8*)&lds[sl][d16] = *(const u16x8*)src;
  *(u16x8*)&lds[sl][d16 + 8] = *(const u16x8*)(src + 8);
  __syncthreads();
  int dl = t >> 2, s16 = (t & 3) << 4;
  u16x8 o0, o1;
#pragma unroll
  for (int i = 0; i < 8; ++i) o0[i] = lds[s16 + i][dl];
#pragma unroll
  for (int i = 0; i < 8; ++i) o1[i] = lds[s16 + 8 + i][dl];
  u16t* dst = vt + ((size_t)bh * 64 + dl) * 2048 + s0 + s16;
  *(u16x8*)&dst[0] = o0;
  *(u16x8*)&dst[8] = o1;
}

// ---------------- causal flash attention ----------------
// grid: (B*H, S/128). Block: 256 threads (4 waves), each wave 32 q-rows.
// KV block = 64. Q in regs (pre-scaled by 1/sqrt(64)), K row-major LDS,
// V transposed [d][kv] in LDS, P relaid out via per-wave swizzled LDS.
__global__ __launch_bounds__(256) void k_attn(const u16t* __restrict__ qkv,
                                              const u16t* __restrict__ vt,
                                              u16t* __restrict__ outp) {
  __shared__ u16t Kl[64 * 64];
  __shared__ u16t Vl[64 * 64];
  __shared__ u16t Pl[4][32 * 64];
  const int tid = threadIdx.x, l = tid & 63, w = tid >> 6;
  const int bh = blockIdx.x, b = bh >> 4, h = bh & 15;
  const int qt = gridDim.y - 1 - blockIdx.y;  // big tiles dispatch first
  const int q0 = qt * 128;
  const int nt = (q0 >> 6) + 2;
  const int lm = l & 15, lh = l >> 4;

  // Q fragments, scaled by 0.125 (exact in bf16)
  bf16x8 aq[2][2];
#pragma unroll
  for (int m = 0; m < 2; ++m)
#pragma unroll
    for (int kk = 0; kk < 2; ++kk) {
      int row = q0 + w * 32 + m * 16 + lm;
      const u16t* src =
          qkv + (size_t)(b * 2048 + row) * 3072 + h * 64 + kk * 32 + lh * 8;
      u16x8 v = *(const u16x8*)src;
      u16x8 o;
#pragma unroll
      for (int e = 0; e < 8; ++e) o[e] = f2bf(bf2f(v[e]) * 0.125f);
      aq[m][kk] = __builtin_bit_cast(bf16x8, o);
    }

  float mrun[2][4], lrun[2][4];
  f32x4 aco[2][4] = {};
#pragma unroll
  for (int m = 0; m < 2; ++m)
#pragma unroll
    for (int r = 0; r < 4; ++r) {
      mrun[m][r] = -1e30f;
      lrun[m][r] = 0.f;
    }

  const u16t* Kg = qkv + (size_t)b * 2048 * 3072 + 1024 + h * 64;
  const u16t* Vg = vt + (size_t)bh * 64 * 2048;
  u16t* Pw = &Pl[w][0];

  for (int t = 0; t < nt; ++t) {
#pragma unroll
    for (int s = 0; s < 2; ++s) {
      int c = s * 256 + tid;
      int row = c >> 3, slot = c & 7;
      gload_lds16(Kg + (size_t)(t * 64 + row) * 3072 + (((slot ^ (row & 7)) & 7) << 3),
                  &Kl[c * 8]);
    }
#pragma unroll
    for (int s = 0; s < 2; ++s) {
      int c = s * 256 + tid;
      int row = c >> 3, slot = c & 7;
      gload_lds16(Vg + (size_t)row * 2048 + t * 64 + (((slot ^ (row & 7)) & 7) << 3),
                  &Vl[c * 8]);
    }
    asm volatile("s_waitcnt vmcnt(0)" ::: "memory");
    __syncthreads();

    // S = Q K^T
    f32x4 accs[2][4] = {};
#pragma unroll
    for (int kk = 0; kk < 2; ++kk) {
      bf16x8 bk[4];
#pragma unroll
      for (int n = 0; n < 4; ++n) {
        int rk = n * 16 + lm;
        int sk = (kk * 4 + lh) ^ (rk & 7);
        bk[n] = ldsfrag(&Kl[rk * 64 + sk * 8]);
      }
#pragma unroll
      for (int m = 0; m < 2; ++m)
#pragma unroll
        for (int n = 0; n < 4; ++n)
          accs[m][n] = __builtin_amdgcn_mfma_f32_16x16x32_bf16(aq[m][kk], bk[n],
                                                               accs[m][n], 0, 0, 0);
    }

    // causal mask + online softmax (rows live in 16-lane groups)
#pragma unroll
    for (int m = 0; m < 2; ++m) {
      int qg = q0 + w * 32 + m * 16 + lh * 4;
#pragma unroll
      for (int r = 0; r < 4; ++r) {
        float vmax = -1e30f;
#pragma unroll
        for (int n = 0; n < 4; ++n) {
          int kvg = t * 64 + n * 16 + lm;
          float v = accs[m][n][r];
          v = (kvg > qg + r) ? -1e30f : v;
          accs[m][n][r] = v;
          vmax = fmaxf(vmax, v);
        }
#pragma unroll
        for (int off = 1; off < 16; off <<= 1)
          vmax = fmaxf(vmax, __shfl_xor(vmax, off));
        float mnew = fmaxf(mrun[m][r], vmax);
        float alpha = __expf(mrun[m][r] - mnew);
        mrun[m][r] = mnew;
        float rs = 0.f;
#pragma unroll
        for (int n = 0; n < 4; ++n) {
          float p = __expf(accs[m][n][r] - mnew);
          accs[m][n][r] = p;
          rs += p;
        }
#pragma unroll
        for (int off = 1; off < 16; off <<= 1) rs += __shfl_xor(rs, off);
        lrun[m][r] = lrun[m][r] * alpha + rs;
#pragma unroll
        for (int nd = 0; nd < 4; ++nd) aco[m][nd][r] *= alpha;
      }
    }

    // P -> per-wave swizzled LDS (relayout D-frag -> A-frag)
#pragma unroll
    for (int m = 0; m < 2; ++m)
#pragma unroll
      for (int n = 0; n < 4; ++n)
#pragma unroll
        for (int r = 0; r < 4; ++r) {
          int prow = m * 16 + lh * 4 + r;
          int pcol = n * 16 + lm;
          int off = prow * 64 + ((((pcol >> 3) ^ (prow & 7)) & 7) << 3) + (pcol & 7);
          Pw[off] = f2bf(accs[m][n][r]);
        }

    // O += P V
#pragma unroll
    for (int kk = 0; kk < 2; ++kk) {
      bf16x8 bv[4], ap[2];
#pragma unroll
      for (int nd = 0; nd < 4; ++nd) {
        int rv = nd * 16 + lm;
        int sv = (kk * 4 + lh) ^ (rv & 7);
        bv[nd] = ldsfrag(&Vl[rv * 64 + sv * 8]);
      }
#pragma unroll
      for (int m = 0; m < 2; ++m) {
        int ra = m * 16 + lm;
        int sa = (kk * 4 + lh) ^ (ra & 7);
        ap[m] = ldsfrag(&Pw[ra * 64 + sa * 8]);
      }
#pragma unroll
      for (int m = 0; m < 2; ++m)
#pragma unroll
        for (int nd = 0; nd < 4; ++nd)
          aco[m][nd] = __builtin_amdgcn_mfma_f32_16x16x32_bf16(ap[m], bv[nd],
                                                               aco[m][nd], 0, 0, 0);
    }
    __syncthreads();
  }

  // epilogue: normalize and store
#pragma unroll
  for (int m = 0; m < 2; ++m)
#pragma unroll
    for (int r = 0; r < 4; ++r) {
      float inv = 1.0f / lrun[m][r];
      int row = q0 + w * 32 + m * 16 + lh * 4 + r;
#pragma unroll
      for (int nd = 0; nd < 4; ++nd) {
        int col = h * 64 + nd * 16 + lm;
        outp[(size_t)(b * 2048 + row) * 1024 + col] = f2bf(aco[m][nd][r] * inv);
      }
    }
}

extern "C" void kernel_launch(void* const* d_in, const int* in_sizes, int n_in,
                              void* d_out, int out_size, void* d_ws, size_t ws_size,
                              hipStream_t stream) {
  const float* x = (const float*)d_in[0];
  const float* wq = (const float*)d_in[1];
  const float* bq = (const float*)d_in[2];
  const float* wk = (const float*)d_in[3];
  const float* bk = (const float*)d_in[4];
  const float* wv = (const float*)d_in[5];
  const float* bv = (const float*)d_in[6];
  const float* wo = (const float*)d_in[7];
  const float* bo = (const float*)d_in[8];

  char* ws = (char*)d_ws;
  u16t* xb = (u16t*)ws;                          //  8 MB: x bf16 (later reused as attn_out)
  u16t* wqkvT = (u16t*)(ws + (8u << 20));        //  6 MB: [wq^T; wk^T; wv^T] bf16
  u16t* woT = (u16t*)(ws + (14u << 20));         //  2 MB: wo^T bf16
  u16t* qkv = (u16t*)(ws + (16u << 20));         // 24 MB: [4096][3072] bf16
  u16t* vt = (u16t*)(ws + (40u << 20));          //  8 MB: [32][64][2048] bf16
  u16t* attn_out = xb;

  k_convert_x<<<4096, 256, 0, stream>>>(x, xb);
  k_transw<<<dim3(16, 16, 4), 256, 0, stream>>>(wq, wk, wv, wo, wqkvT, woT);
  k_gemm_bt<true><<<dim3(32, 24), 256, 0, stream>>>(xb, wqkvT, qkv, bq, bk, bv,
                                                    4096, 3072, 1024);
  k_transv<<<dim3(32, 32), 256, 0, stream>>>(qkv, vt);
  k_attn<<<dim3(32, 16), 256, 0, stream>>>(qkv, vt, attn_out);
  k_gemm_bt<false><<<dim3(32, 8), 256, 0, stream>>>(attn_out, woT, d_out, bo, bo,
                                                    bo, 4096, 1024, 1024);
}

// Round 2
// 130.120 us; speedup vs baseline: 1.3445x; 1.3445x over previous
//
#include <hip/hip_runtime.h>
#include <hip/hip_bf16.h>
#include <cstdint>

#define DEV static __device__ __forceinline__

typedef unsigned short u16t;
typedef __attribute__((ext_vector_type(4))) float f32x4;
typedef __attribute__((ext_vector_type(4))) unsigned short u16x4;
typedef __attribute__((ext_vector_type(8))) unsigned short u16x8;
typedef __attribute__((ext_vector_type(8))) __bf16 bf16x8;

DEV u16t f2bf(float f) {
  unsigned u = __builtin_bit_cast(unsigned, f);
  u += 0x7fffu + ((u >> 16) & 1u);
  return (u16t)(u >> 16);
}
DEV float bf2f(u16t h) {
  unsigned u = ((unsigned)h) << 16;
  return __builtin_bit_cast(float, u);
}

DEV void gload_lds16(const void* g, void* l) {
  __builtin_amdgcn_global_load_lds(
      (const __attribute__((address_space(1))) void*)g,
      (__attribute__((address_space(3))) void*)l, 16, 0, 0);
}

DEV bf16x8 ldsfrag(const u16t* p) {
  return __builtin_bit_cast(bf16x8, *(const u16x8*)p);
}

// ---------------- convert x (fp32 -> bf16) ----------------
__global__ __launch_bounds__(256) void k_convert_x(const float* __restrict__ x,
                                                   u16t* __restrict__ xb) {
  int i = (blockIdx.x * 256 + threadIdx.x) * 4;
  f32x4 v = *(const f32x4*)&x[i];
  u16x4 o;
#pragma unroll
  for (int j = 0; j < 4; ++j) o[j] = f2bf(v[j]);
  *(u16x4*)&xb[i] = o;
}

// ------------- transpose + convert weights (fp32 [K][N] -> bf16 [N][K]) -------------
__global__ __launch_bounds__(256) void k_transw(const float* __restrict__ w0,
                                                const float* __restrict__ w1,
                                                const float* __restrict__ w2,
                                                const float* __restrict__ w3,
                                                u16t* __restrict__ qkvT,
                                                u16t* __restrict__ oT) {
  __shared__ float lds[64][68];
  int z = blockIdx.z;
  const float* W = (z == 0) ? w0 : (z == 1) ? w1 : (z == 2) ? w2 : w3;
  u16t* OUT = (z < 3) ? (qkvT + (size_t)z * 1024 * 1024) : oT;
  int k0 = blockIdx.x * 64, n0 = blockIdx.y * 64;
  int t = threadIdx.x;
  int kl = t >> 4, n4 = (t & 15) << 2;
#pragma unroll
  for (int p = 0; p < 4; ++p) {
    f32x4 v = *(const f32x4*)&W[(size_t)(k0 + kl + p * 16) * 1024 + n0 + n4];
    *(f32x4*)&lds[kl + p * 16][n4] = v;
  }
  __syncthreads();
  int nl = t >> 4, k4 = (t & 15) << 2;
#pragma unroll
  for (int p = 0; p < 4; ++p) {
    int n = nl + p * 16;
    u16x4 o;
#pragma unroll
    for (int i = 0; i < 4; ++i) o[i] = f2bf(lds[k4 + i][n]);
    *(u16x4*)&OUT[(size_t)(n0 + n) * 1024 + k0 + k4] = o;
  }
}

// ---------------- GEMM: C[M,N] = A[M,K] * BT[N,K]^T + bias ----------------
template <bool BF16_OUT>
__global__ __launch_bounds__(256) void k_gemm_bt(const u16t* __restrict__ A,
                                                 const u16t* __restrict__ BT,
                                                 void* __restrict__ Cout,
                                                 const float* __restrict__ b0,
                                                 const float* __restrict__ b1,
                                                 const float* __restrict__ b2,
                                                 int M, int N, int K) {
  __shared__ u16t Al[128 * 64];
  __shared__ u16t Bl[128 * 64];
  const int tid = threadIdx.x;
  const int l = tid & 63;
  const int w = tid >> 6;
  const int m0 = blockIdx.x * 128, n0 = blockIdx.y * 128;
  const int wm = (w >> 1) * 64, wn = (w & 1) * 64;
  const int lm = l & 15, lh = l >> 4;
  f32x4 acc[4][4] = {};

  const int nt = K >> 6;
  for (int t = 0; t < nt; ++t) {
    const int k0 = t << 6;
#pragma unroll
    for (int s = 0; s < 4; ++s) {
      int c = s * 256 + tid;
      int row = c >> 3, slot = c & 7;
      int ks = k0 + (((slot ^ (row & 7)) & 7) << 3);
      gload_lds16(A + (size_t)(m0 + row) * K + ks, &Al[c * 8]);
    }
#pragma unroll
    for (int s = 0; s < 4; ++s) {
      int c = s * 256 + tid;
      int row = c >> 3, slot = c & 7;
      int ks = k0 + (((slot ^ (row & 7)) & 7) << 3);
      gload_lds16(BT + (size_t)(n0 + row) * K + ks, &Bl[c * 8]);
    }
    asm volatile("s_waitcnt vmcnt(0)" ::: "memory");
    __syncthreads();

#pragma unroll
    for (int kk = 0; kk < 2; ++kk) {
      bf16x8 af[4], bfr[4];
#pragma unroll
      for (int i = 0; i < 4; ++i) {
        int ra = wm + i * 16 + lm;
        int sa = (kk * 4 + lh) ^ (ra & 7);
        af[i] = ldsfrag(&Al[ra * 64 + sa * 8]);
        int rb = wn + i * 16 + lm;
        int sb = (kk * 4 + lh) ^ (rb & 7);
        bfr[i] = ldsfrag(&Bl[rb * 64 + sb * 8]);
      }
#pragma unroll
      for (int i = 0; i < 4; ++i)
#pragma unroll
        for (int j = 0; j < 4; ++j)
          acc[i][j] = __builtin_amdgcn_mfma_f32_16x16x32_bf16(af[i], bfr[j],
                                                              acc[i][j], 0, 0, 0);
    }
    __syncthreads();
  }

#pragma unroll
  for (int i = 0; i < 4; ++i) {
    int row = m0 + wm + i * 16 + (lh << 2);
#pragma unroll
    for (int j = 0; j < 4; ++j) {
      int col = n0 + wn + j * 16 + lm;
      const float* bp = (col < 1024) ? b0 : ((col < 2048) ? b1 : b2);
      float bias = bp[col & 1023];
#pragma unroll
      for (int r = 0; r < 4; ++r) {
        float v = acc[i][j][r] + bias;
        if (BF16_OUT)
          ((u16t*)Cout)[(size_t)(row + r) * N + col] = f2bf(v);
        else
          ((float*)Cout)[(size_t)(row + r) * N + col] = v;
      }
    }
  }
}

// ---------------- transpose V: qkv[:, 2048+h*64+d] -> vt[bh][d][s] ----------------
__global__ __launch_bounds__(256) void k_transv(const u16t* __restrict__ qkv,
                                                u16t* __restrict__ vt) {
  __shared__ u16t lds[64][80];
  int bh = blockIdx.y, b = bh >> 4, h = bh & 15;
  int s0 = blockIdx.x * 64;
  int t = threadIdx.x;
  int sl = t >> 2, d16 = (t & 3) << 4;
  const u16t* src = qkv + (size_t)(b * 2048 + s0 + sl) * 3072 + 2048 + h * 64 + d16;
  *(u16x8*)&lds[sl][d16] = *(const u16x8*)src;
  *(u16x8*)&lds[sl][d16 + 8] = *(const u16x8*)(src + 8);
  __syncthreads();
  int dl = t >> 2, s16 = (t & 3) << 4;
  u16x8 o0, o1;
#pragma unroll
  for (int i = 0; i < 8; ++i) o0[i] = lds[s16 + i][dl];
#pragma unroll
  for (int i = 0; i < 8; ++i) o1[i] = lds[s16 + 8 + i][dl];
  u16t* dst = vt + ((size_t)bh * 64 + dl) * 2048 + s0 + s16;
  *(u16x8*)&dst[0] = o0;
  *(u16x8*)&dst[8] = o1;
}

// ---------------- causal flash attention (swapped QK^T, defer-max) ----------------
// grid: (B*H=32, 32 q-tiles of 64 rows). Block: 256 threads = 4 waves, each wave
// owns 16 q-rows. KV tile = 64, double-buffered LDS. Softmax row = lane&15
// (lane-local stats, no shuffles in common path, THR=8 defer-max).
__global__ __launch_bounds__(256, 4) void k_attn(const u16t* __restrict__ qkv,
                                                 const u16t* __restrict__ vt,
                                                 u16t* __restrict__ outp) {
  __shared__ u16t Kl[2][4096];  // [kv=64][d=64], 16B-slot swizzled
  __shared__ u16t Vl[2][4096];  // [d=64][kv=64], 16B-slot swizzled
  __shared__ u16t Pl[4][1024];  // per-wave P [q=16][kv=64], swizzled
  const int tid = threadIdx.x, l = tid & 63, w = tid >> 6;
  const int lm = l & 15, lh = l >> 4;
  const int bh = blockIdx.x, b = bh >> 4, h = bh & 15;
  // balanced qt permutation: each CU's 4 resident blocks sum to equal work
  const int y = blockIdx.y;
  const int kg = y >> 3, jj = y & 7;
  const int qt = kg * 8 + ((kg & 1) ? (7 - jj) : jj);
  const int q0 = qt * 64;
  const int nt = qt + 1;

  // Q fragment (B-operand layout), pre-scaled by 1/sqrt(64)=0.125 (exact in bf16)
  bf16x8 aq[2];
  const int qrow = q0 + w * 16 + lm;
#pragma unroll
  for (int kk = 0; kk < 2; ++kk) {
    const u16t* src = qkv + (size_t)(b * 2048 + qrow) * 3072 + h * 64 + kk * 32 + lh * 8;
    u16x8 v = *(const u16x8*)src;
    u16x8 o;
#pragma unroll
    for (int e = 0; e < 8; ++e) o[e] = f2bf(bf2f(v[e]) * 0.125f);
    aq[kk] = __builtin_bit_cast(bf16x8, o);
  }

  float mrun = -1e30f;  // running max of row `qrow` (replicated over lh)
  float lsum = 0.f;     // per-lane PARTIAL sum of row `qrow` (this lane's kv slots)
  f32x4 aco[4] = {};    // O[q=lh*4+r][d=nd*16+lm]

  const u16t* Kg = qkv + (size_t)b * 2048 * 3072 + 1024 + h * 64;
  const u16t* Vg = vt + (size_t)bh * 64 * 2048;
  u16t* Pw = &Pl[w][0];

  auto stage = [&](int buf, int t) {
#pragma unroll
    for (int s = 0; s < 2; ++s) {
      int c = s * 256 + tid;
      int row = c >> 3, col = ((c & 7) ^ (row & 7)) << 3;
      gload_lds16(Kg + (size_t)(t * 64 + row) * 3072 + col, &Kl[buf][c * 8]);
    }
#pragma unroll
    for (int s = 0; s < 2; ++s) {
      int c = s * 256 + tid;
      int row = c >> 3, col = ((c & 7) ^ (row & 7)) << 3;
      gload_lds16(Vg + (size_t)row * 2048 + t * 64 + col, &Vl[buf][c * 8]);
    }
  };

  stage(0, 0);
  asm volatile("s_waitcnt vmcnt(0)" ::: "memory");
  __syncthreads();

  int buf = 0;
  for (int t = 0; t < nt; ++t) {
    if (t + 1 < nt) stage(buf ^ 1, t + 1);

    // S^T = K * Q : accs[nk] holds S^T[kv=nk*16+lh*4+r][q=lm]
    f32x4 accs[4] = {};
#pragma unroll
    for (int kk = 0; kk < 2; ++kk) {
      bf16x8 ak[4];
#pragma unroll
      for (int nk = 0; nk < 4; ++nk) {
        int rk = nk * 16 + lm;
        int s16 = (kk * 4 + lh) ^ (rk & 7);
        ak[nk] = ldsfrag(&Kl[buf][rk * 64 + s16 * 8]);
      }
      __builtin_amdgcn_s_setprio(1);
#pragma unroll
      for (int nk = 0; nk < 4; ++nk)
        accs[nk] = __builtin_amdgcn_mfma_f32_16x16x32_bf16(ak[nk], aq[kk],
                                                           accs[nk], 0, 0, 0);
      __builtin_amdgcn_s_setprio(0);
    }

    // causal mask + per-lane tile max
    float vmax = -1e30f;
#pragma unroll
    for (int nk = 0; nk < 4; ++nk)
#pragma unroll
      for (int r = 0; r < 4; ++r) {
        int kvpos = t * 64 + nk * 16 + lh * 4 + r;
        float v = accs[nk][r];
        v = (kvpos > qrow) ? -1e30f : v;
        accs[nk][r] = v;
        vmax = fmaxf(vmax, v);
      }

    // defer-max: rare path only when tile max exceeds running max by >8
    if (!__all(vmax <= mrun + 8.f)) {
      float rm = fmaxf(vmax, __shfl_xor(vmax, 16));
      rm = fmaxf(rm, __shfl_xor(rm, 32));
      float mnew = fmaxf(mrun, rm);
      float alpha = __expf(mrun - mnew);
      mrun = mnew;
      lsum *= alpha;
#pragma unroll
      for (int r = 0; r < 4; ++r) {
        float ar = __shfl(alpha, lh * 4 + r);
#pragma unroll
        for (int nd = 0; nd < 4; ++nd) aco[nd][r] *= ar;
      }
    }

    // p = exp(s - mrun); accumulate partial lsum; pack 4 bf16 -> one b64 LDS write
#pragma unroll
    for (int nk = 0; nk < 4; ++nk) {
      u16x4 pb;
#pragma unroll
      for (int r = 0; r < 4; ++r) {
        float p = __expf(accs[nk][r] - mrun);
        lsum += p;
        pb[r] = f2bf(p);
      }
      int s16 = (nk * 2 + (lh >> 1)) ^ (lm & 7);
      *(u16x4*)&Pw[lm * 64 + s16 * 8 + (lh & 1) * 4] = pb;
    }

    // O += P * V
#pragma unroll
    for (int kk = 0; kk < 2; ++kk) {
      int s16p = (kk * 4 + lh) ^ (lm & 7);
      bf16x8 ap = ldsfrag(&Pw[lm * 64 + s16p * 8]);
      __builtin_amdgcn_s_setprio(1);
#pragma unroll
      for (int nd = 0; nd < 4; ++nd) {
        int rv = nd * 16 + lm;
        int s16v = (kk * 4 + lh) ^ (rv & 7);
        bf16x8 bv = ldsfrag(&Vl[buf][rv * 64 + s16v * 8]);
        aco[nd] = __builtin_amdgcn_mfma_f32_16x16x32_bf16(ap, bv, aco[nd], 0, 0, 0);
      }
      __builtin_amdgcn_s_setprio(0);
    }

    asm volatile("s_waitcnt vmcnt(0)" ::: "memory");
    __syncthreads();
    buf ^= 1;
  }

  // epilogue: finish lsum reduce, normalize, store
  lsum += __shfl_xor(lsum, 16);
  lsum += __shfl_xor(lsum, 32);
  float inv = 1.0f / lsum;  // for row `qrow` (lane lm)
#pragma unroll
  for (int r = 0; r < 4; ++r) {
    float ir = __shfl(inv, lh * 4 + r);
    int row = q0 + w * 16 + lh * 4 + r;
#pragma unroll
    for (int nd = 0; nd < 4; ++nd) {
      int col = h * 64 + nd * 16 + lm;
      outp[(size_t)(b * 2048 + row) * 1024 + col] = f2bf(aco[nd][r] * ir);
    }
  }
}

extern "C" void kernel_launch(void* const* d_in, const int* in_sizes, int n_in,
                              void* d_out, int out_size, void* d_ws, size_t ws_size,
                              hipStream_t stream) {
  const float* x = (const float*)d_in[0];
  const float* wq = (const float*)d_in[1];
  const float* bq = (const float*)d_in[2];
  const float* wk = (const float*)d_in[3];
  const float* bk = (const float*)d_in[4];
  const float* wv = (const float*)d_in[5];
  const float* bv = (const float*)d_in[6];
  const float* wo = (const float*)d_in[7];
  const float* bo = (const float*)d_in[8];

  char* ws = (char*)d_ws;
  u16t* xb = (u16t*)ws;                    //  8 MB: x bf16 (later reused as attn_out)
  u16t* wqkvT = (u16t*)(ws + (8u << 20));  //  6 MB: [wq^T; wk^T; wv^T] bf16
  u16t* woT = (u16t*)(ws + (14u << 20));   //  2 MB: wo^T bf16
  u16t* qkv = (u16t*)(ws + (16u << 20));   // 24 MB: [4096][3072] bf16
  u16t* vt = (u16t*)(ws + (40u << 20));    //  8 MB: [32][64][2048] bf16
  u16t* attn_out = xb;

  k_convert_x<<<4096, 256, 0, stream>>>(x, xb);
  k_transw<<<dim3(16, 16, 4), 256, 0, stream>>>(wq, wk, wv, wo, wqkvT, woT);
  k_gemm_bt<true><<<dim3(32, 24), 256, 0, stream>>>(xb, wqkvT, qkv, bq, bk, bv,
                                                    4096, 3072, 1024);
  k_transv<<<dim3(32, 32), 256, 0, stream>>>(qkv, vt);
  k_attn<<<dim3(32, 32), 256, 0, stream>>>(qkv, vt, attn_out);
  k_gemm_bt<false><<<dim3(32, 8), 256, 0, stream>>>(attn_out, woT, d_out, bo, bo,
                                                    bo, 4096, 1024, 1024);
}